// Round 13
// baseline (373.149 us; speedup 1.0000x reference)
//
#include <hip/hip_runtime.h>
#include <math.h>

#define D 64
#define CAP 64    // bucket = 64 ints = 256B; P(deg>64)~5e-16 for Poisson(16)

typedef __attribute__((ext_vector_type(8))) short bf16x8;   // 8 bf16 = 4 VGPRs
typedef __attribute__((ext_vector_type(4))) float f32x4;    // MFMA C/D

__device__ __forceinline__ float lrelu(float x, float s) { return x > 0.f ? x : s * x; }

// f32 -> bf16 round-to-nearest-even
__device__ __forceinline__ unsigned f2bf(float f) {
    unsigned b = __builtin_bit_cast(unsigned, f);
    return (b + 0x7fffu + ((b >> 16) & 1u)) >> 16;
}
__device__ __forceinline__ float bf2f(unsigned u) { return __builtin_bit_cast(float, u << 16); }
__device__ __forceinline__ float bflo(unsigned u) { return __builtin_bit_cast(float, u << 16); }
__device__ __forceinline__ float bfhi(unsigned u) { return __builtin_bit_cast(float, u & 0xffff0000u); }

// ---- readlane mm (R9 known-good): layer-1 inside the fused kernel ----
__device__ __forceinline__ void mm_rows(const float* __restrict__ xin,
        const float* __restrict__ W, const float* __restrict__ a_src, const float* __restrict__ a_dst,
        unsigned* __restrict__ hb, float* __restrict__ ssrc, float* __restrict__ sdst,
        int N, int worker, int nworkers, int lane, int wv) {
    float w[D];
    #pragma unroll
    for (int k = 0; k < D; ++k) w[k] = W[k * D + lane];   // column `lane`
    float asv = a_src[lane], adv = a_dst[lane];
    for (int r = worker * 4 + wv; r < N; r += nworkers * 4) {
        float v = xin[(size_t)r * D + lane];
        int vi = __builtin_bit_cast(int, v);
        float a0 = 0.f, a1 = 0.f, a2 = 0.f, a3 = 0.f;
        #pragma unroll
        for (int k = 0; k < D; k += 4) {
            float b0 = __builtin_bit_cast(float, __builtin_amdgcn_readlane(vi, k + 0));
            float b1 = __builtin_bit_cast(float, __builtin_amdgcn_readlane(vi, k + 1));
            float b2 = __builtin_bit_cast(float, __builtin_amdgcn_readlane(vi, k + 2));
            float b3 = __builtin_bit_cast(float, __builtin_amdgcn_readlane(vi, k + 3));
            a0 = fmaf(b0, w[k + 0], a0);
            a1 = fmaf(b1, w[k + 1], a1);
            a2 = fmaf(b2, w[k + 2], a2);
            a3 = fmaf(b3, w[k + 3], a3);
        }
        float acc = (a0 + a1) + (a2 + a3);
        float accp = __shfl_xor(acc, 1, 64);
        unsigned packed = f2bf(acc) | (f2bf(accp) << 16);
        if (!(lane & 1)) hb[(size_t)r * 32 + (lane >> 1)] = packed;
        float v1 = acc * asv, v2 = acc * adv;
        #pragma unroll
        for (int off = 32; off; off >>= 1) {
            v1 += __shfl_xor(v1, off, 64);
            v2 += __shfl_xor(v2, off, 64);
        }
        if (lane == 0) { ssrc[r] = v1; sdst[r] = v2; }
    }
}

// ---- MFMA mm (layouts verified R10/R11): layer-2. One wave = 16x64 tile.
// Split-precision bf16 (AhWh + AlWh + AhWl) ~ fp32. No LDS; shfl epilogue.
__device__ __forceinline__ void mfma_mm(const float* __restrict__ xin,
        const float* __restrict__ W, const float* __restrict__ a_src, const float* __restrict__ a_dst,
        const float* __restrict__ bn_sum, const float* __restrict__ bn_sumsq,
        const float* __restrict__ gamma, const float* __restrict__ beta,
        unsigned* __restrict__ hb, float* __restrict__ ssrc, float* __restrict__ sdst,
        int N, int worker, int nworkers) {
    int lane = threadIdx.x & 63;
    int q = lane >> 4, r16 = lane & 15;
    bf16x8 bh[2][4], bl[2][4];
    for (int kt = 0; kt < 2; ++kt)
        for (int tc = 0; tc < 4; ++tc) {
            bf16x8 vh, vl;
            #pragma unroll
            for (int j = 0; j < 8; ++j) {
                float w = W[(kt * 32 + q * 8 + j) * D + tc * 16 + r16];
                unsigned hbits = f2bf(w);
                float r = w - bf2f(hbits);
                vh[j] = (short)hbits; vl[j] = (short)f2bf(r);
            }
            bh[kt][tc] = vh; bl[kt][tc] = vl;
        }
    float scA[2][8], shA[2][8];
    for (int kt = 0; kt < 2; ++kt)
        #pragma unroll
        for (int j = 0; j < 8; ++j) {
            int c = kt * 32 + q * 8 + j;
            float mu = bn_sum[c] / (float)N;
            float var = bn_sumsq[c] / (float)N - mu * mu;   // biased var = jnp.var
            float rs = rsqrtf(var + 1e-5f);
            float sc = rs * gamma[c];
            scA[kt][j] = sc; shA[kt][j] = beta[c] - mu * sc;
        }
    float asv[4], adv[4];
    #pragma unroll
    for (int tc = 0; tc < 4; ++tc) { asv[tc] = a_src[tc * 16 + r16]; adv[tc] = a_dst[tc * 16 + r16]; }

    int ntiles = (N + 15) >> 4;
    for (int tix = worker; tix < ntiles; tix += nworkers) {
        int r0 = tix << 4;
        int rowA = r0 + r16;
        int rowc = rowA < N ? rowA : N - 1;
        bf16x8 ah[2], al[2];
        #pragma unroll
        for (int kt = 0; kt < 2; ++kt) {
            const float4* p = (const float4*)(xin + (size_t)rowc * D + kt * 32 + q * 8);
            float4 x0 = p[0], x1 = p[1];
            float v[8] = {x0.x, x0.y, x0.z, x0.w, x1.x, x1.y, x1.z, x1.w};
            bf16x8 vh, vl;
            #pragma unroll
            for (int j = 0; j < 8; ++j) {
                float u = v[j];
                u = u * scA[kt][j] + shA[kt][j]; u = u > 0.f ? u : 0.01f * u;
                unsigned hbits = f2bf(u);
                float r = u - bf2f(hbits);
                vh[j] = (short)hbits; vl[j] = (short)f2bf(r);
            }
            ah[kt] = vh; al[kt] = vl;
        }
        f32x4 acc[4] = {{0.f,0.f,0.f,0.f},{0.f,0.f,0.f,0.f},{0.f,0.f,0.f,0.f},{0.f,0.f,0.f,0.f}};
        #pragma unroll
        for (int kt = 0; kt < 2; ++kt)
            #pragma unroll
            for (int tc = 0; tc < 4; ++tc) {
                acc[tc] = __builtin_amdgcn_mfma_f32_16x16x32_bf16(ah[kt], bh[kt][tc], acc[tc], 0, 0, 0);
                acc[tc] = __builtin_amdgcn_mfma_f32_16x16x32_bf16(al[kt], bh[kt][tc], acc[tc], 0, 0, 0);
                acc[tc] = __builtin_amdgcn_mfma_f32_16x16x32_bf16(ah[kt], bl[kt][tc], acc[tc], 0, 0, 0);
            }
        float d1[4], d2[4];
        #pragma unroll
        for (int reg = 0; reg < 4; ++reg) {
            float p1 = 0.f, p2 = 0.f;
            #pragma unroll
            for (int tc = 0; tc < 4; ++tc) {
                p1 = fmaf(acc[tc][reg], asv[tc], p1);
                p2 = fmaf(acc[tc][reg], adv[tc], p2);
            }
            #pragma unroll
            for (int off = 1; off < 16; off <<= 1) {
                p1 += __shfl_xor(p1, off, 64);
                p2 += __shfl_xor(p2, off, 64);
            }
            d1[reg] = p1; d2[reg] = p2;
        }
        if (r16 == 0) {
            #pragma unroll
            for (int reg = 0; reg < 4; ++reg) {
                int row = r0 + q * 4 + reg;
                if (row < N) { ssrc[row] = d1[reg]; sdst[row] = d2[reg]; }
            }
        }
        #pragma unroll
        for (int tc = 0; tc < 4; ++tc)
            #pragma unroll
            for (int reg = 0; reg < 4; ++reg) {
                float mine = acc[tc][reg];
                float part = __shfl_xor(mine, 1, 64);
                if (!(r16 & 1)) {
                    int row = r0 + q * 4 + reg;
                    if (row < N)
                        hb[(size_t)row * 32 + tc * 8 + (r16 >> 1)] =
                            f2bf(mine) | (f2bf(part) << 16);
                }
            }
    }
}

// Fused (R9/R12): even blocks = bucket fill (x4 independent atomic chains,
// 1024 blocks = measured sweet spot); odd blocks = layer-1 readlane mm.
__global__ __launch_bounds__(256) void k_fill_mm1(const int* __restrict__ ei, int E,
        int* __restrict__ cnt, int* __restrict__ col,
        const float* __restrict__ xin, const float* __restrict__ W,
        const float* __restrict__ a_src, const float* __restrict__ a_dst,
        unsigned* __restrict__ hb, float* __restrict__ ssrc, float* __restrict__ sdst, int N) {
    int tid = threadIdx.x, lane = tid & 63, wv = tid >> 6;
    int nb = gridDim.x;
    if ((blockIdx.x & 1) == 0) {
        int f = blockIdx.x >> 1;
        int nf = nb >> 1;
        int idx = f * 256 + tid;
        int stride = nf * 256;
        const int4* s4 = (const int4*)ei;
        const int4* d4 = (const int4*)(ei + E);
        int nq = E >> 2;
        for (int i = idx; i < nq; i += stride) {
            int4 s = s4[i];
            int4 d = d4[i];
            int q0 = atomicAdd(&cnt[d.x], 1);
            int q1 = atomicAdd(&cnt[d.y], 1);
            int q2 = atomicAdd(&cnt[d.z], 1);
            int q3 = atomicAdd(&cnt[d.w], 1);
            if (q0 < CAP) col[((size_t)d.x << 6) + q0] = s.x;
            if (q1 < CAP) col[((size_t)d.y << 6) + q1] = s.y;
            if (q2 < CAP) col[((size_t)d.z << 6) + q2] = s.z;
            if (q3 < CAP) col[((size_t)d.w << 6) + q3] = s.w;
        }
        if (f == 0 && tid < (E & 3)) {
            int i = (nq << 2) + tid;
            int s = ei[i], d = ei[E + i];
            int q = atomicAdd(&cnt[d], 1);
            if (q < CAP) col[((size_t)d << 6) + q] = s;
        }
    } else {
        int m = blockIdx.x >> 1;
        int nm = nb >> 1;
        mm_rows(xin, W, a_src, a_dst, hb, ssrc, sdst, N, m, nm, lane, wv);
    }
}

// standalone layer-2 MFMA mm (BN+leaky folded into A prep)
__global__ void k_mm2(const float* __restrict__ t,
        const float* __restrict__ W, const float* __restrict__ a_src, const float* __restrict__ a_dst,
        const float* __restrict__ bn_sum, const float* __restrict__ bn_sumsq,
        const float* __restrict__ gamma, const float* __restrict__ beta,
        unsigned* __restrict__ hb, float* __restrict__ ssrc, float* __restrict__ sdst, int N) {
    int tid = threadIdx.x;
    mfma_mm(t, W, a_src, a_dst, bn_sum, bn_sumsq, gamma, beta,
            hb, ssrc, sdst, N, blockIdx.x * 4 + (tid >> 6), gridDim.x * 4);
}

// One wave per dst node, single-pass exact softmax. 3-stage node pipeline +
// x4-unrolled edge loop (16 h-gathers in flight; 1 iteration for typical dg~16).
__global__ __launch_bounds__(256) void k_csr_agg(const int* __restrict__ col,
        const int* __restrict__ cnt,
        const float* __restrict__ ssrc, const float* __restrict__ sdst,
        const unsigned* __restrict__ hb, const float* __restrict__ bias,
        const float* __restrict__ x, float* __restrict__ out,
        float* __restrict__ bn_sum, float* __restrict__ bn_sumsq, int mode, int N) {
    __shared__ float sbn1[D], sbn2[D];
    int tid = threadIdx.x;
    int lane = tid & 63;
    int sub = lane >> 4;
    int sl = lane & 15;
    if (mode == 0) {
        if (tid < D) { sbn1[tid] = 0.f; sbn2[tid] = 0.f; }
        __syncthreads();
    }
    int wid = (blockIdx.x * 256 + tid) >> 6;
    int stride = (gridDim.x * 256) >> 6;
    const uint2* h2 = (const uint2*)hb;
    float4 s1 = make_float4(0, 0, 0, 0), s2 = make_float4(0, 0, 0, 0);

    auto loadA = [&](int node, int& dg, int& sal, float& ssn, float& sdn) {
        int nn = (node < N) ? node : wid;
        int dgl = cnt[nn]; dgl = dgl > CAP ? CAP : dgl;
        int s = col[((size_t)nn << 6) + lane];
        sal = (lane < dgl) ? s : nn;
        dg = dgl;
        ssn = ssrc[nn]; sdn = sdst[nn];
    };

    if (wid < N) {
        int dg0, sal0, dg1, sal1;
        float ssn0, sdn0, ssn1, sdn1, g0;
        loadA(wid, dg0, sal0, ssn0, sdn0);
        loadA(wid + stride, dg1, sal1, ssn1, sdn1);
        g0 = ssrc[sal0];

        for (int n = wid; n < N; n += stride) {
            int dg2, sal2; float ssn2, sdn2;
            loadA(n + 2 * stride, dg2, sal2, ssn2, sdn2);
            float g1 = ssrc[sal1];

            float e_all = (lane < dg0) ? __expf(lrelu(g0 + sdn0, 0.2f)) : 0.f;
            float z = e_all;
            #pragma unroll
            for (int off = 32; off; off >>= 1) z += __shfl_xor(z, off, 64);
            float es = __expf(lrelu(ssn0 + sdn0, 0.2f));
            z += es;
            float4 acc = make_float4(0, 0, 0, 0);
            if (sub == 0) {
                uint2 hv = h2[(size_t)n * 16 + sl];
                acc.x = es * bflo(hv.x); acc.y = es * bfhi(hv.x);
                acc.z = es * bflo(hv.y); acc.w = es * bfhi(hv.y);
            }
            int dgr = (dg0 + 15) & ~15;      // x4 unroll: 16 edges in flight
            for (int j = sub; j < dgr; j += 16) {
                int sA = __shfl(sal0, j, 64);
                float eA = __shfl(e_all, j, 64);
                int sB = __shfl(sal0, j + 4, 64);
                float eB = __shfl(e_all, j + 4, 64);
                int sC = __shfl(sal0, j + 8, 64);
                float eC = __shfl(e_all, j + 8, 64);
                int sD = __shfl(sal0, j + 12, 64);
                float eD = __shfl(e_all, j + 12, 64);
                uint2 hA = h2[(size_t)sA * 16 + sl];
                uint2 hB = h2[(size_t)sB * 16 + sl];
                uint2 hC = h2[(size_t)sC * 16 + sl];
                uint2 hD = h2[(size_t)sD * 16 + sl];
                acc.x = fmaf(eA, bflo(hA.x), acc.x); acc.y = fmaf(eA, bfhi(hA.x), acc.y);
                acc.z = fmaf(eA, bflo(hA.y), acc.z); acc.w = fmaf(eA, bfhi(hA.y), acc.w);
                acc.x = fmaf(eB, bflo(hB.x), acc.x); acc.y = fmaf(eB, bfhi(hB.x), acc.y);
                acc.z = fmaf(eB, bflo(hB.y), acc.z); acc.w = fmaf(eB, bfhi(hB.y), acc.w);
                acc.x = fmaf(eC, bflo(hC.x), acc.x); acc.y = fmaf(eC, bfhi(hC.x), acc.y);
                acc.z = fmaf(eC, bflo(hC.y), acc.z); acc.w = fmaf(eC, bfhi(hC.y), acc.w);
                acc.x = fmaf(eD, bflo(hD.x), acc.x); acc.y = fmaf(eD, bfhi(hD.x), acc.y);
                acc.z = fmaf(eD, bflo(hD.y), acc.z); acc.w = fmaf(eD, bfhi(hD.y), acc.w);
            }
            #pragma unroll
            for (int off = 16; off <= 32; off <<= 1) {
                acc.x += __shfl_xor(acc.x, off, 64);
                acc.y += __shfl_xor(acc.y, off, 64);
                acc.z += __shfl_xor(acc.z, off, 64);
                acc.w += __shfl_xor(acc.w, off, 64);
            }
            if (sub == 0) {
                float inv = 1.f / z;
                float4 b4 = ((const float4*)bias)[sl];
                float4 v;
                v.x = acc.x * inv + b4.x; v.y = acc.y * inv + b4.y;
                v.z = acc.z * inv + b4.z; v.w = acc.w * inv + b4.w;
                if (mode == 0) {
                    ((float4*)out)[(size_t)n * 16 + sl] = v;
                    s1.x += v.x; s1.y += v.y; s1.z += v.z; s1.w += v.w;
                    s2.x += v.x * v.x; s2.y += v.y * v.y; s2.z += v.z * v.z; s2.w += v.w * v.w;
                } else {
                    float4 xv = ((const float4*)x)[(size_t)n * 16 + sl];
                    v.x = 0.5f * (xv.x + v.x); v.y = 0.5f * (xv.y + v.y);
                    v.z = 0.5f * (xv.z + v.z); v.w = 0.5f * (xv.w + v.w);
                    ((float4*)out)[(size_t)n * 16 + sl] = v;
                }
            }
            dg0 = dg1; sal0 = sal1; ssn0 = ssn1; sdn0 = sdn1; g0 = g1;
            dg1 = dg2; sal1 = sal2; ssn1 = ssn2; sdn1 = sdn2;
        }
    }
    if (mode == 0) {
        if (sub == 0) {
            int c = sl * 4;
            atomicAdd(&sbn1[c + 0], s1.x); atomicAdd(&sbn1[c + 1], s1.y);
            atomicAdd(&sbn1[c + 2], s1.z); atomicAdd(&sbn1[c + 3], s1.w);
            atomicAdd(&sbn2[c + 0], s2.x); atomicAdd(&sbn2[c + 1], s2.y);
            atomicAdd(&sbn2[c + 2], s2.z); atomicAdd(&sbn2[c + 3], s2.w);
        }
        __syncthreads();
        if (tid < D) {
            atomicAdd(&bn_sum[tid], sbn1[tid]);
            atomicAdd(&bn_sumsq[tid], sbn2[tid]);
        }
    }
}

extern "C" void kernel_launch(void* const* d_in, const int* in_sizes, int n_in,
                              void* d_out, int out_size, void* d_ws, size_t ws_size,
                              hipStream_t stream) {
    const float* x     = (const float*)d_in[0];
    const float* W1    = (const float*)d_in[1];
    const float* as1   = (const float*)d_in[2];
    const float* ad1   = (const float*)d_in[3];
    const float* b1    = (const float*)d_in[4];
    const float* gamma = (const float*)d_in[5];
    const float* beta  = (const float*)d_in[6];
    const float* W2    = (const float*)d_in[7];
    const float* as2   = (const float*)d_in[8];
    const float* ad2   = (const float*)d_in[9];
    const float* b2    = (const float*)d_in[10];
    const int*   ei    = (const int*)d_in[11];
    int N = in_sizes[0] / D;
    int E = in_sizes[11] / 2;
    float* out = (float*)d_out;          // reused as layer-1 output buffer (fp32)

    float* ws = (float*)d_ws;
    unsigned* hb = (unsigned*)ws;                 // bf16-packed h: N*32 uints (12.8MB)
    float* ssrc = (float*)(hb + (size_t)N * 32);
    float* sdst = ssrc + N;
    int* cnt    = (int*)(sdst + N);               // N (contiguous with bn for one memset)
    float* bn   = (float*)(cnt + N);              // 128: sum(64) | sumsq(64)
    int* colarr = (int*)(bn + 128);               // N*CAP (25.6MB)

    dim3 blk(256);

    // zero cnt + bn in one async memset
    hipMemsetAsync(cnt, 0, (size_t)N * 4 + 512, stream);

    // ---- fused: bucket fill (1024 blocks) + layer-1 readlane mm (1024) ----
    k_fill_mm1<<<2048, blk, 0, stream>>>(ei, E, cnt, colarr,
                                         x, W1, as1, ad1, hb, ssrc, sdst, N);

    // ---- layer 1 aggregate ----
    k_csr_agg<<<2048, blk, 0, stream>>>(colarr, cnt, ssrc, sdst, hb, b1,
                                        nullptr, out, bn, bn + 64, 0, N);

    // ---- layer 2 mm (MFMA, BN folded, 2048 workers) ----
    k_mm2<<<512, blk, 0, stream>>>(out, W2, as2, ad2, bn, bn + 64, gamma, beta,
                                   hb, ssrc, sdst, N);

    // ---- layer 2 aggregate + final mix ----
    k_csr_agg<<<2048, blk, 0, stream>>>(colarr, cnt, ssrc, sdst, hb, b2,
                                        x, out, bn, bn + 64, 1, N);
}

// Round 14
// 358.743 us; speedup vs baseline: 1.0402x; 1.0402x over previous
//
#include <hip/hip_runtime.h>
#include <math.h>

#define D 64
#define CAP 64    // bucket = 64 ints = 256B; P(deg>64)~5e-16 for Poisson(16)

__device__ __forceinline__ float lrelu(float x, float s) { return x > 0.f ? x : s * x; }

// f32 -> bf16 round-to-nearest-even
__device__ __forceinline__ unsigned f2bf(float f) {
    unsigned b = __builtin_bit_cast(unsigned, f);
    return (b + 0x7fffu + ((b >> 16) & 1u)) >> 16;
}
__device__ __forceinline__ float bflo(unsigned u) { return __builtin_bit_cast(float, u << 16); }
__device__ __forceinline__ float bfhi(unsigned u) { return __builtin_bit_cast(float, u & 0xffff0000u); }

// readlane mm (R9 known-good): W column in 64 VGPRs, x-row broadcast via v_readlane.
__device__ __forceinline__ void mm_rows(const float* __restrict__ xin,
        const float* __restrict__ W, const float* __restrict__ a_src, const float* __restrict__ a_dst,
        const float* __restrict__ bn_sum, const float* __restrict__ bn_sumsq,
        const float* __restrict__ gamma, const float* __restrict__ beta, int apply_bn,
        unsigned* __restrict__ hb, float* __restrict__ ssrc, float* __restrict__ sdst,
        int N, int worker, int nworkers, int lane, int wv) {
    float w[D];
    #pragma unroll
    for (int k = 0; k < D; ++k) w[k] = W[k * D + lane];   // column `lane`
    float asv = a_src[lane], adv = a_dst[lane];
    float sc = 1.f, sh = 0.f;
    if (apply_bn) {
        float mu = bn_sum[lane] / (float)N;
        float var = bn_sumsq[lane] / (float)N - mu * mu;   // biased var = jnp.var
        float rs = rsqrtf(var + 1e-5f);
        sc = rs * gamma[lane];
        sh = beta[lane] - mu * sc;
    }
    for (int r = worker * 4 + wv; r < N; r += nworkers * 4) {
        float v = xin[(size_t)r * D + lane];
        if (apply_bn) { v = v * sc + sh; v = v > 0.f ? v : 0.01f * v; }
        int vi = __builtin_bit_cast(int, v);
        float a0 = 0.f, a1 = 0.f, a2 = 0.f, a3 = 0.f;   // 4 chains break FMA latency
        #pragma unroll
        for (int k = 0; k < D; k += 4) {
            float b0 = __builtin_bit_cast(float, __builtin_amdgcn_readlane(vi, k + 0));
            float b1 = __builtin_bit_cast(float, __builtin_amdgcn_readlane(vi, k + 1));
            float b2 = __builtin_bit_cast(float, __builtin_amdgcn_readlane(vi, k + 2));
            float b3 = __builtin_bit_cast(float, __builtin_amdgcn_readlane(vi, k + 3));
            a0 = fmaf(b0, w[k + 0], a0);
            a1 = fmaf(b1, w[k + 1], a1);
            a2 = fmaf(b2, w[k + 2], a2);
            a3 = fmaf(b3, w[k + 3], a3);
        }
        float acc = (a0 + a1) + (a2 + a3);
        float accp = __shfl_xor(acc, 1, 64);
        unsigned packed = f2bf(acc) | (f2bf(accp) << 16);
        if (!(lane & 1)) hb[(size_t)r * 32 + (lane >> 1)] = packed;
        float v1 = acc * asv, v2 = acc * adv;
        #pragma unroll
        for (int off = 32; off; off >>= 1) {
            v1 += __shfl_xor(v1, off, 64);
            v2 += __shfl_xor(v2, off, 64);
        }
        if (lane == 0) { ssrc[r] = v1; sdst[r] = v2; }
    }
}

// Fused (R9 exact): even blocks = bucket fill (x4 independent atomic chains,
// 1024 fill blocks = measured sweet spot); odd blocks = layer-1 readlane mm.
__global__ __launch_bounds__(256) void k_fill_mm1(const int* __restrict__ ei, int E,
        int* __restrict__ cnt, int* __restrict__ col,
        const float* __restrict__ xin, const float* __restrict__ W,
        const float* __restrict__ a_src, const float* __restrict__ a_dst,
        unsigned* __restrict__ hb, float* __restrict__ ssrc, float* __restrict__ sdst, int N) {
    int tid = threadIdx.x, lane = tid & 63, wv = tid >> 6;
    int nb = gridDim.x;
    if ((blockIdx.x & 1) == 0) {
        int f = blockIdx.x >> 1;
        int nf = nb >> 1;
        int idx = f * 256 + tid;
        int stride = nf * 256;
        const int4* s4 = (const int4*)ei;
        const int4* d4 = (const int4*)(ei + E);
        int nq = E >> 2;
        for (int i = idx; i < nq; i += stride) {
            int4 s = s4[i];
            int4 d = d4[i];
            int q0 = atomicAdd(&cnt[d.x], 1);
            int q1 = atomicAdd(&cnt[d.y], 1);
            int q2 = atomicAdd(&cnt[d.z], 1);
            int q3 = atomicAdd(&cnt[d.w], 1);
            if (q0 < CAP) col[((size_t)d.x << 6) + q0] = s.x;
            if (q1 < CAP) col[((size_t)d.y << 6) + q1] = s.y;
            if (q2 < CAP) col[((size_t)d.z << 6) + q2] = s.z;
            if (q3 < CAP) col[((size_t)d.w << 6) + q3] = s.w;
        }
        if (f == 0 && tid < (E & 3)) {
            int i = (nq << 2) + tid;
            int s = ei[i], d = ei[E + i];
            int q = atomicAdd(&cnt[d], 1);
            if (q < CAP) col[((size_t)d << 6) + q] = s;
        }
    } else {
        int m = blockIdx.x >> 1;
        int nm = nb >> 1;
        mm_rows(xin, W, a_src, a_dst, nullptr, nullptr, nullptr, nullptr, 0,
                hb, ssrc, sdst, N, m, nm, lane, wv);
    }
}

// standalone layer-2 readlane mm (BN folded in) — R9 config (beat MFMA by A/B R9/R12)
__global__ __launch_bounds__(256) void k_mm_att(const float* __restrict__ xin,
        const float* __restrict__ W, const float* __restrict__ a_src, const float* __restrict__ a_dst,
        const float* __restrict__ bn_sum, const float* __restrict__ bn_sumsq,
        const float* __restrict__ gamma, const float* __restrict__ beta,
        unsigned* __restrict__ hb, float* __restrict__ ssrc, float* __restrict__ sdst, int N) {
    int tid = threadIdx.x, lane = tid & 63, wv = tid >> 6;
    mm_rows(xin, W, a_src, a_dst, bn_sum, bn_sumsq, gamma, beta, 1,
            hb, ssrc, sdst, N, blockIdx.x, gridDim.x, lane, wv);
}

// One wave per dst node, single-pass exact softmax. 3-stage node pipeline +
// x2-unrolled edge loop (R9). NEW: col bucket load exec-masked to lane<dg
// (cuts bucket fetch 256B -> ~dg*4B rounded to lines; -18MB FETCH per dispatch).
__global__ __launch_bounds__(256) void k_csr_agg(const int* __restrict__ col,
        const int* __restrict__ cnt,
        const float* __restrict__ ssrc, const float* __restrict__ sdst,
        const unsigned* __restrict__ hb, const float* __restrict__ bias,
        const float* __restrict__ x, float* __restrict__ out,
        float* __restrict__ bn_sum, float* __restrict__ bn_sumsq, int mode, int N) {
    __shared__ float sbn1[D], sbn2[D];
    int tid = threadIdx.x;
    int lane = tid & 63;
    int sub = lane >> 4;
    int sl = lane & 15;
    if (mode == 0) {
        if (tid < D) { sbn1[tid] = 0.f; sbn2[tid] = 0.f; }
        __syncthreads();
    }
    int wid = (blockIdx.x * 256 + tid) >> 6;
    int stride = (gridDim.x * 256) >> 6;
    const uint2* h2 = (const uint2*)hb;
    float4 s1 = make_float4(0, 0, 0, 0), s2 = make_float4(0, 0, 0, 0);

    auto loadA = [&](int node, int& dg, int& sal, float& ssn, float& sdn) {
        int nn = (node < N) ? node : wid;
        int dgl = cnt[nn]; dgl = dgl > CAP ? CAP : dgl;
        // exec-masked bucket load: only lanes < dg touch memory
        sal = (lane < dgl) ? col[((size_t)nn << 6) + lane] : nn;
        dg = dgl;
        ssn = ssrc[nn]; sdn = sdst[nn];
    };

    if (wid < N) {
        int dg0, sal0, dg1, sal1;
        float ssn0, sdn0, ssn1, sdn1, g0;
        loadA(wid, dg0, sal0, ssn0, sdn0);
        loadA(wid + stride, dg1, sal1, ssn1, sdn1);
        g0 = ssrc[sal0];

        for (int n = wid; n < N; n += stride) {
            int dg2, sal2; float ssn2, sdn2;
            loadA(n + 2 * stride, dg2, sal2, ssn2, sdn2);
            float g1 = ssrc[sal1];

            float e_all = (lane < dg0) ? __expf(lrelu(g0 + sdn0, 0.2f)) : 0.f;
            float z = e_all;
            #pragma unroll
            for (int off = 32; off; off >>= 1) z += __shfl_xor(z, off, 64);
            float es = __expf(lrelu(ssn0 + sdn0, 0.2f));
            z += es;
            float4 acc = make_float4(0, 0, 0, 0);
            if (sub == 0) {
                uint2 hv = h2[(size_t)n * 16 + sl];
                acc.x = es * bflo(hv.x); acc.y = es * bfhi(hv.x);
                acc.z = es * bflo(hv.y); acc.w = es * bfhi(hv.y);
            }
            int dgr = (dg0 + 7) & ~7;
            for (int j = sub; j < dgr; j += 8) {
                int sA = __shfl(sal0, j, 64);
                float eA = __shfl(e_all, j, 64);
                int sB = __shfl(sal0, j + 4, 64);
                float eB = __shfl(e_all, j + 4, 64);
                uint2 hA = h2[(size_t)sA * 16 + sl];
                uint2 hB = h2[(size_t)sB * 16 + sl];
                acc.x = fmaf(eA, bflo(hA.x), acc.x); acc.y = fmaf(eA, bfhi(hA.x), acc.y);
                acc.z = fmaf(eA, bflo(hA.y), acc.z); acc.w = fmaf(eA, bfhi(hA.y), acc.w);
                acc.x = fmaf(eB, bflo(hB.x), acc.x); acc.y = fmaf(eB, bfhi(hB.x), acc.y);
                acc.z = fmaf(eB, bflo(hB.y), acc.z); acc.w = fmaf(eB, bfhi(hB.y), acc.w);
            }
            #pragma unroll
            for (int off = 16; off <= 32; off <<= 1) {
                acc.x += __shfl_xor(acc.x, off, 64);
                acc.y += __shfl_xor(acc.y, off, 64);
                acc.z += __shfl_xor(acc.z, off, 64);
                acc.w += __shfl_xor(acc.w, off, 64);
            }
            if (sub == 0) {
                float inv = 1.f / z;
                float4 b4 = ((const float4*)bias)[sl];
                float4 v;
                v.x = acc.x * inv + b4.x; v.y = acc.y * inv + b4.y;
                v.z = acc.z * inv + b4.z; v.w = acc.w * inv + b4.w;
                if (mode == 0) {
                    ((float4*)out)[(size_t)n * 16 + sl] = v;
                    s1.x += v.x; s1.y += v.y; s1.z += v.z; s1.w += v.w;
                    s2.x += v.x * v.x; s2.y += v.y * v.y; s2.z += v.z * v.z; s2.w += v.w * v.w;
                } else {
                    float4 xv = ((const float4*)x)[(size_t)n * 16 + sl];
                    v.x = 0.5f * (xv.x + v.x); v.y = 0.5f * (xv.y + v.y);
                    v.z = 0.5f * (xv.z + v.z); v.w = 0.5f * (xv.w + v.w);
                    ((float4*)out)[(size_t)n * 16 + sl] = v;
                }
            }
            dg0 = dg1; sal0 = sal1; ssn0 = ssn1; sdn0 = sdn1; g0 = g1;
            dg1 = dg2; sal1 = sal2; ssn1 = ssn2; sdn1 = sdn2;
        }
    }
    if (mode == 0) {
        if (sub == 0) {
            int c = sl * 4;
            atomicAdd(&sbn1[c + 0], s1.x); atomicAdd(&sbn1[c + 1], s1.y);
            atomicAdd(&sbn1[c + 2], s1.z); atomicAdd(&sbn1[c + 3], s1.w);
            atomicAdd(&sbn2[c + 0], s2.x); atomicAdd(&sbn2[c + 1], s2.y);
            atomicAdd(&sbn2[c + 2], s2.z); atomicAdd(&sbn2[c + 3], s2.w);
        }
        __syncthreads();
        if (tid < D) {
            atomicAdd(&bn_sum[tid], sbn1[tid]);
            atomicAdd(&bn_sumsq[tid], sbn2[tid]);
        }
    }
}

extern "C" void kernel_launch(void* const* d_in, const int* in_sizes, int n_in,
                              void* d_out, int out_size, void* d_ws, size_t ws_size,
                              hipStream_t stream) {
    const float* x     = (const float*)d_in[0];
    const float* W1    = (const float*)d_in[1];
    const float* as1   = (const float*)d_in[2];
    const float* ad1   = (const float*)d_in[3];
    const float* b1    = (const float*)d_in[4];
    const float* gamma = (const float*)d_in[5];
    const float* beta  = (const float*)d_in[6];
    const float* W2    = (const float*)d_in[7];
    const float* as2   = (const float*)d_in[8];
    const float* ad2   = (const float*)d_in[9];
    const float* b2    = (const float*)d_in[10];
    const int*   ei    = (const int*)d_in[11];
    int N = in_sizes[0] / D;
    int E = in_sizes[11] / 2;
    float* out = (float*)d_out;          // reused as layer-1 output buffer (fp32)

    float* ws = (float*)d_ws;
    unsigned* hb = (unsigned*)ws;                 // bf16-packed h: N*32 uints (12.8MB)
    float* ssrc = (float*)(hb + (size_t)N * 32);
    float* sdst = ssrc + N;
    int* cnt    = (int*)(sdst + N);               // N (contiguous with bn for one memset)
    float* bn   = (float*)(cnt + N);              // 128: sum(64) | sumsq(64)
    int* colarr = (int*)(bn + 128);               // N*CAP (25.6MB)

    dim3 blk(256);

    // zero cnt + bn in one async memset
    hipMemsetAsync(cnt, 0, (size_t)N * 4 + 512, stream);

    // ---- fused: bucket fill (1024 blocks) + layer-1 readlane mm (1024) ----
    k_fill_mm1<<<2048, blk, 0, stream>>>(ei, E, cnt, colarr,
                                         x, W1, as1, ad1, hb, ssrc, sdst, N);

    // ---- layer 1 aggregate ----
    k_csr_agg<<<2048, blk, 0, stream>>>(colarr, cnt, ssrc, sdst, hb, b1,
                                        nullptr, out, bn, bn + 64, 0, N);

    // ---- layer 2 mm (readlane, BN folded) ----
    k_mm_att<<<2048, blk, 0, stream>>>(out, W2, as2, ad2, bn, bn + 64, gamma, beta,
                                       hb, ssrc, sdst, N);

    // ---- layer 2 aggregate + final mix ----
    k_csr_agg<<<2048, blk, 0, stream>>>(colarr, cnt, ssrc, sdst, hb, b2,
                                        x, out, bn, bn + 64, 1, N);
}